// Round 13
// baseline (215.001 us; speedup 1.0000x reference)
//
#include <hip/hip_runtime.h>
#include <hip/hip_bf16.h>

#define N_NODES 200000
#define N_EDGES 640000
#define D_NODE 128
#define D_EDGE 32
#define HIDDEN 128
#define KTOT 288          // 128 (x) + 128 (Sx) + 32 (Sea)

using bf16x8  = __attribute__((ext_vector_type(8))) short;
using f32x4   = __attribute__((ext_vector_type(4))) float;
using short4v = __attribute__((ext_vector_type(4))) short;

__device__ __forceinline__ short f2b(float f) {
  return __builtin_bit_cast(short, __float2bfloat16(f));
}
__device__ __forceinline__ float b2f(short s) {
  unsigned u = ((unsigned)(unsigned short)s) << 16;
  return __builtin_bit_cast(float, u);
}

// ===========================================================================
// k_histwc: [0,2500): hist (latency-bound, lingers);  [2500,2645): Wc build
// ===========================================================================
#define HIST_NB 2500    // N_EDGES/256
#define WC_NB   145     // ceil((288*128 + 128)/256)

__global__ __launch_bounds__(256) void k_histwc(
    const int* __restrict__ ei, int* cnt, int* slot,
    const float* __restrict__ W1, const float* __restrict__ b1,
    const float* __restrict__ W2, short* __restrict__ WcT,
    float* __restrict__ bc)
{
  const int b = blockIdx.x;
  if (b < HIST_NB) {
    const int e = b * 256 + threadIdx.x;
    slot[e] = atomicAdd(&cnt[ei[N_EDGES + e]], 1);
  } else {
    const int t = (b - HIST_NB) * 256 + threadIdx.x;
    if (t < 288 * 128) {
      const int brow = t >> 7, c = t & 127;
      if (brow < 128) {
        WcT[c * KTOT + brow] = f2b(W2[brow * 128 + c]);
      } else {
        const int i = brow - 128;
        float acc = 0.f;
        #pragma unroll 8
        for (int q = 0; q < 128; ++q)
          acc += W1[i * 128 + q] * W2[(128 + q) * 128 + c];
        WcT[c * KTOT + brow] = f2b(acc);
      }
    } else if (t < 288 * 128 + 128) {
      const int c = t - 288 * 128;
      float acc = 0.f;
      #pragma unroll 8
      for (int q = 0; q < 128; ++q)
        acc += b1[q] * W2[(128 + q) * 128 + c];
      bc[c] = acc;
    }
  }
}

// ===========================================================================
// CSR scans (round-12 proven)
// ===========================================================================
#define SCAN_NB 196  // ceil(200000/1024)

__global__ __launch_bounds__(256) void k_scan_a(const int* __restrict__ cnt,
                                                int* bsum) {
  __shared__ int sh[256];
  const int b = blockIdx.x, t = threadIdx.x;
  const int base = b * 1024 + t * 4;
  int s = 0;
  #pragma unroll
  for (int k = 0; k < 4; ++k) {
    const int idx = base + k;
    s += (idx < N_NODES) ? cnt[idx] : 0;
  }
  sh[t] = s; __syncthreads();
  for (int o = 128; o > 0; o >>= 1) {
    if (t < o) sh[t] += sh[t + o];
    __syncthreads();
  }
  if (t == 0) bsum[b] = sh[0];
}

__global__ __launch_bounds__(256) void k_scan_c2(const int* __restrict__ cnt,
                                                 const int* __restrict__ bsum,
                                                 int* offv) {
  __shared__ int sh[256];
  __shared__ int base_sh;
  const int b = blockIdx.x, t = threadIdx.x;

  sh[t] = (t < SCAN_NB && t < b) ? bsum[t] : 0;
  __syncthreads();
  for (int o = 128; o > 0; o >>= 1) {
    if (t < o) sh[t] += sh[t + o];
    __syncthreads();
  }
  if (t == 0) base_sh = sh[0];
  __syncthreads();

  const int base = b * 1024 + t * 4;
  int v[4], p[4], s = 0;
  #pragma unroll
  for (int k = 0; k < 4; ++k) {
    const int idx = base + k;
    v[k] = (idx < N_NODES) ? cnt[idx] : 0;
    p[k] = s; s += v[k];
  }
  sh[t] = s; __syncthreads();
  const int tot = s;
  for (int o = 1; o < 256; o <<= 1) {
    const int tv = (t >= o) ? sh[t - o] : 0;
    __syncthreads();
    sh[t] += tv;
    __syncthreads();
  }
  const int gb = base_sh + (sh[t] - tot);
  #pragma unroll
  for (int k = 0; k < 4; ++k) {
    const int idx = base + k;
    if (idx < N_NODES) offv[idx] = gb + p[k];
  }
}

// ===========================================================================
// k_placeprep: [0,2500): place (scatter, latency-bound, dispatched FIRST so
//   it lingers);  [2500,15000): x->bf16 xb streaming (backfills idle BW).
// ===========================================================================
#define PLACE_NB 2500
#define PREP_NB  12500   // N_NODES*16/256

__global__ __launch_bounds__(256) void k_placeprep(
    const int* __restrict__ ei, const int* __restrict__ offv,
    const int* __restrict__ slot, const float* __restrict__ ea,
    int* __restrict__ psrc, short* __restrict__ ea_s,
    const float* __restrict__ x, short* __restrict__ xb)
{
  const int b = blockIdx.x;
  if (b < PLACE_NB) {
    const int e = b * 256 + threadIdx.x;
    const int j = offv[ei[N_EDGES + e]] + slot[e];
    psrc[j] = ei[e];
    #pragma unroll
    for (int h = 0; h < 4; ++h) {
      const float4 w0 = *(const float4*)&ea[(size_t)e * D_EDGE + h * 8];
      const float4 w1 = *(const float4*)&ea[(size_t)e * D_EDGE + h * 8 + 4];
      bf16x8 o = { f2b(w0.x), f2b(w0.y), f2b(w0.z), f2b(w0.w),
                   f2b(w1.x), f2b(w1.y), f2b(w1.z), f2b(w1.w) };
      *(bf16x8*)&ea_s[(size_t)j * D_EDGE + h * 8] = o;
    }
  } else {
    const int i = (b - PLACE_NB) * 256 + threadIdx.x;
    const int node = i >> 4;
    const int oct  = (i & 15) << 3;
    const float4 v0 = *(const float4*)&x[(size_t)node * D_NODE + oct];
    const float4 v1 = *(const float4*)&x[(size_t)node * D_NODE + oct + 4];
    bf16x8 o = { f2b(v0.x), f2b(v0.y), f2b(v0.z), f2b(v0.w),
                 f2b(v1.x), f2b(v1.y), f2b(v1.z), f2b(v1.w) };
    *(bf16x8*)&xb[(size_t)node * D_NODE + oct] = o;
  }
}

// ===========================================================================
// S aggregation (round-12 proven, dense arrays)
// ===========================================================================
__global__ __launch_bounds__(256) void k_sagg4(
    const int* __restrict__ offv, const int* __restrict__ cnt,
    const int* __restrict__ psrc, const short* __restrict__ xb,
    const short* __restrict__ ea_s,
    short* __restrict__ Sx, short* __restrict__ Se)
{
  const int gtid = blockIdx.x * 256 + threadIdx.x;
  if (gtid < N_NODES * 16) {
    const int node = gtid >> 4;
    const int oct8 = (gtid & 15) << 3;
    const int s0 = offv[node];
    const int s1 = s0 + cnt[node];
    float a[8] = {};
    int j = s0;
    while (j < s1) {
      const int rem = s1 - j;
      bf16x8 v0, v1, v2, v3;
      v0 = *(const bf16x8*)&xb[(size_t)psrc[j] * D_NODE + oct8];
      if (rem > 1) v1 = *(const bf16x8*)&xb[(size_t)psrc[j + 1] * D_NODE + oct8];
      if (rem > 2) v2 = *(const bf16x8*)&xb[(size_t)psrc[j + 2] * D_NODE + oct8];
      if (rem > 3) v3 = *(const bf16x8*)&xb[(size_t)psrc[j + 3] * D_NODE + oct8];
      #pragma unroll
      for (int k = 0; k < 8; ++k) a[k] += b2f(v0[k]);
      if (rem > 1) {
        #pragma unroll
        for (int k = 0; k < 8; ++k) a[k] += b2f(v1[k]);
      }
      if (rem > 2) {
        #pragma unroll
        for (int k = 0; k < 8; ++k) a[k] += b2f(v2[k]);
      }
      if (rem > 3) {
        #pragma unroll
        for (int k = 0; k < 8; ++k) a[k] += b2f(v3[k]);
      }
      j += 4;
    }
    bf16x8 o;
    #pragma unroll
    for (int k = 0; k < 8; ++k) o[k] = f2b(a[k]);
    *(bf16x8*)&Sx[(size_t)node * D_NODE + oct8] = o;
  } else {
    const int t2 = gtid - N_NODES * 16;       // 0 .. N_NODES*4
    const int node = t2 >> 2;
    const int q8   = (t2 & 3) << 3;           // 8 bf16 = 16B
    const int s0 = offv[node];
    const int s1 = s0 + cnt[node];
    float a[8] = {};
    for (int j = s0; j < s1; ++j) {
      const bf16x8 v = *(const bf16x8*)&ea_s[(size_t)j * D_EDGE + q8];
      #pragma unroll
      for (int k = 0; k < 8; ++k) a[k] += b2f(v[k]);
    }
    bf16x8 o;
    #pragma unroll
    for (int k = 0; k < 8; ++k) o[k] = f2b(a[k]);
    *(bf16x8*)&Se[(size_t)node * D_EDGE + q8] = o;
  }
}

// ===========================================================================
// Output GEMM (round-12 proven): out = [xb|Sx|Se] @ Wc + cnt*bc + b2.
// ===========================================================================
#define LDP 104   // 96+8 bf16: 208B rows -> 2-way bank alias only (free)

__global__ __launch_bounds__(256, 4) void k_out2(
    const short* __restrict__ xb, const short* __restrict__ Sx,
    const short* __restrict__ Se, const short* __restrict__ WcT,
    const float* __restrict__ bc, const float* __restrict__ b2,
    const int* __restrict__ cnt, float* __restrict__ out)
{
  __shared__ short smem[64 * LDP + 128 * LDP];   // 39936 B
  short* lA = smem;
  short* lB = smem + 64 * LDP;
  const int tid = threadIdx.x;
  const int n0  = blockIdx.x * 64;

  const int lane = tid & 63;
  const int wid  = tid >> 6;
  const int wm = wid >> 1, wn = wid & 1;          // 2x2 waves, 32x64 out each
  const int lrow = lane & 15;
  const int lk   = (lane >> 4) << 3;

  f32x4 acc[2][4] = {};

  #pragma unroll
  for (int p = 0; p < 3; ++p) {
    for (int i = tid; i < 1536; i += 256) {       // lB: 128 rows x 12 octs
      const int n = i / 12, ck = (i % 12) << 3;
      *(bf16x8*)&lB[n * LDP + ck] = *(const bf16x8*)&WcT[n * KTOT + p * 96 + ck];
    }
    for (int i = tid; i < 768; i += 256) {        // lA: 64 rows x 12 octs
      const int m = i / 12, ck = (i % 12) << 3;
      const int k = p * 96 + ck;
      const int node = n0 + m;
      const short* src;
      if (k < 128)      src = &xb[(size_t)node * D_NODE + k];
      else if (k < 256) src = &Sx[(size_t)node * D_NODE + (k - 128)];
      else              src = &Se[(size_t)node * D_EDGE + (k - 256)];
      *(bf16x8*)&lA[m * LDP + ck] = *(const bf16x8*)src;
    }
    __syncthreads();
    #pragma unroll
    for (int kt = 0; kt < 3; ++kt) {
      const int ks = kt * 32 + lk;
      bf16x8 af[2], bfr[4];
      #pragma unroll
      for (int i = 0; i < 2; ++i)
        af[i]  = *(const bf16x8*)&lA[(wm * 32 + i * 16 + lrow) * LDP + ks];
      #pragma unroll
      for (int j = 0; j < 4; ++j)
        bfr[j] = *(const bf16x8*)&lB[(wn * 64 + j * 16 + lrow) * LDP + ks];
      #pragma unroll
      for (int i = 0; i < 2; ++i)
        #pragma unroll
        for (int j = 0; j < 4; ++j)
          acc[i][j] = __builtin_amdgcn_mfma_f32_16x16x32_bf16(af[i], bfr[j], acc[i][j], 0, 0, 0);
    }
    __syncthreads();
  }

  // ---- epilogue: acc + cnt*bc + b2 -> LDS f32 [64][128] -> coalesced stores
  float* lf = (float*)smem;                       // 32768 B <= 39936 B
  const int rb = wm * 32 + ((lane >> 4) << 2);
  const int cb = wn * 64 + lrow;
  float bcv[4], b2v[4];
  #pragma unroll
  for (int j = 0; j < 4; ++j) {
    bcv[j] = bc[cb + j * 16];
    b2v[j] = b2[cb + j * 16];
  }
  #pragma unroll
  for (int i = 0; i < 2; ++i) {
    #pragma unroll
    for (int r = 0; r < 4; ++r) {
      const int row = rb + i * 16 + r;
      const float cf = (float)cnt[n0 + row];
      #pragma unroll
      for (int j = 0; j < 4; ++j)
        lf[row * 128 + cb + j * 16] = acc[i][j][r] + cf * bcv[j] + b2v[j];
    }
  }
  __syncthreads();
  #pragma unroll
  for (int u = 0; u < 8; ++u) {
    const int idx = tid + u * 256;                // 2048 float4s
    const int row = idx >> 5, f4 = (idx & 31) << 2;
    *(float4*)&out[(size_t)(n0 + row) * HIDDEN + f4] = *(const float4*)&lf[row * 128 + f4];
  }
}

extern "C" void kernel_launch(void* const* d_in, const int* in_sizes, int n_in,
                              void* d_out, int out_size, void* d_ws, size_t ws_size,
                              hipStream_t stream) {
  const float* x  = (const float*)d_in[0];
  const int*   ei = (const int*)d_in[1];
  const float* ea = (const float*)d_in[2];
  const float* W1 = (const float*)d_in[5];
  const float* b1 = (const float*)d_in[6];
  const float* W2 = (const float*)d_in[7];
  const float* b2 = (const float*)d_in[8];
  float* out = (float*)d_out;

  const size_t XB_B   = (size_t)N_NODES * D_NODE * 2; //  51,200,000
  const size_t SX_B   = (size_t)N_NODES * D_NODE * 2; //  51,200,000
  const size_t SE_B   = (size_t)N_NODES * D_EDGE * 2; //  12,800,000
  const size_t WCT_B  = 128 * KTOT * 2;               //      73,728
  const size_t BC_B   = 512;
  const size_t CNT_B  = (size_t)N_NODES * 4;          //     800,000
  const size_t SLOT_B = (size_t)N_EDGES * 4;          //   2,560,000
  const size_t PSRC_B = (size_t)N_EDGES * 4;          //   2,560,000
  const size_t EAS_B  = (size_t)N_EDGES * D_EDGE * 2; //  40,960,000

  const size_t o_xb   = 0;
  const size_t o_sx   = o_xb + XB_B;
  const size_t o_se   = o_sx + SX_B;
  const size_t o_wct  = o_se + SE_B;
  const size_t o_bc   = o_wct + WCT_B;
  const size_t o_cnt  = o_bc + BC_B;
  const size_t o_off  = o_cnt + CNT_B;
  const size_t o_slot = o_off + CNT_B;
  const size_t o_psrc = o_slot + SLOT_B;
  const size_t o_eas  = o_psrc + PSRC_B;
  const size_t o_bsum = o_eas + EAS_B;
  // total ~163.7 MB (round-12 plan fit)

  short* xb   = (short*)((char*)d_ws + o_xb);
  short* Sx   = (short*)((char*)d_ws + o_sx);
  short* Se   = (short*)((char*)d_ws + o_se);
  short* WcT  = (short*)((char*)d_ws + o_wct);
  float* bc   = (float*)((char*)d_ws + o_bc);
  int*   cnt  = (int*)((char*)d_ws + o_cnt);
  int*   offv = (int*)((char*)d_ws + o_off);
  int*   slot = (int*)((char*)d_ws + o_slot);
  int*   psrc = (int*)((char*)d_ws + o_psrc);
  short* ea_s = (short*)((char*)d_ws + o_eas);
  int*   bsum = (int*)((char*)d_ws + o_bsum);

  hipMemsetAsync(cnt, 0, CNT_B, stream);
  k_histwc<<<HIST_NB + WC_NB, 256, 0, stream>>>(ei, cnt, slot, W1, b1, W2, WcT, bc);

  k_scan_a <<<SCAN_NB, 256, 0, stream>>>(cnt, bsum);
  k_scan_c2<<<SCAN_NB, 256, 0, stream>>>(cnt, bsum, offv);

  k_placeprep<<<PLACE_NB + PREP_NB, 256, 0, stream>>>(ei, offv, slot, ea,
                                                      psrc, ea_s, x, xb);

  k_sagg4<<<(N_NODES * 20) / 256, 256, 0, stream>>>(offv, cnt, psrc, xb, ea_s, Sx, Se);
  k_out2 <<<N_NODES / 64, 256, 0, stream>>>(xb, Sx, Se, WcT, bc, b2, cnt, out);
}

// Round 14
// 207.020 us; speedup vs baseline: 1.0386x; 1.0386x over previous
//
#include <hip/hip_runtime.h>
#include <hip/hip_bf16.h>

#define N_NODES 200000
#define N_EDGES 640000
#define D_NODE 128
#define D_EDGE 32
#define HIDDEN 128
#define KTOT 288          // 128 (x) + 128 (Sx) + 32 (Sea)

using bf16x8  = __attribute__((ext_vector_type(8))) short;
using f32x4   = __attribute__((ext_vector_type(4))) float;
using short4v = __attribute__((ext_vector_type(4))) short;

__device__ __forceinline__ short f2b(float f) {
  return __builtin_bit_cast(short, __float2bfloat16(f));
}
__device__ __forceinline__ float b2f(short s) {
  unsigned u = ((unsigned)(unsigned short)s) << 16;
  return __builtin_bit_cast(float, u);
}

// ---------------------------------------------------------------------------
// shared helper: x -> bf16 xb for one prep block (3200B of x per block)
// ---------------------------------------------------------------------------
__device__ __forceinline__ void prep_body(const float* __restrict__ x,
                                          short* __restrict__ xb,
                                          int pblk, int tid) {
  const int i = pblk * 256 + tid;                 // item over half the nodes
  const int node = i >> 4;
  const int oct  = (i & 15) << 3;
  const float4 v0 = *(const float4*)&x[(size_t)node * D_NODE + oct];
  const float4 v1 = *(const float4*)&x[(size_t)node * D_NODE + oct + 4];
  bf16x8 o = { f2b(v0.x), f2b(v0.y), f2b(v0.z), f2b(v0.w),
               f2b(v1.x), f2b(v1.y), f2b(v1.z), f2b(v1.w) };
  *(bf16x8*)&xb[(size_t)node * D_NODE + oct] = o;
}

// ===========================================================================
// k_histprep: modulo-interleaved  hist (2:7)  ||  prepA nodes<100k (5:7)
//   + wc tail blocks.  Co-resident mix -> atomic latency hides under stream.
// ===========================================================================
#define MIX_NB 8750     // 1250 groups * 7;  2:5 split = 2500 hist + 6250 prep
#define WC_NB  145      // ceil((288*128+128)/256)

__global__ __launch_bounds__(256) void k_histprep(
    const int* __restrict__ ei, int* cnt, int* slot,
    const float* __restrict__ x, short* __restrict__ xb,
    const float* __restrict__ W1, const float* __restrict__ b1,
    const float* __restrict__ W2, short* __restrict__ WcT,
    float* __restrict__ bc)
{
  const int b = blockIdx.x;
  const int tid = threadIdx.x;
  if (b < MIX_NB) {
    const int g = b / 7, r = b % 7;
    if (r < 2) {                                  // hist block (0..2499)
      const int e = (g * 2 + r) * 256 + tid;
      slot[e] = atomicAdd(&cnt[ei[N_EDGES + e]], 1);
    } else {                                      // prepA block (0..6249)
      prep_body(x, xb, g * 5 + (r - 2), tid);
    }
  } else {                                        // wc tail
    const int t = (b - MIX_NB) * 256 + tid;
    if (t < 288 * 128) {
      const int brow = t >> 7, c = t & 127;
      if (brow < 128) {
        WcT[c * KTOT + brow] = f2b(W2[brow * 128 + c]);
      } else {
        const int i = brow - 128;
        float acc = 0.f;
        #pragma unroll 8
        for (int q = 0; q < 128; ++q)
          acc += W1[i * 128 + q] * W2[(128 + q) * 128 + c];
        WcT[c * KTOT + brow] = f2b(acc);
      }
    } else if (t < 288 * 128 + 128) {
      const int c = t - 288 * 128;
      float acc = 0.f;
      #pragma unroll 8
      for (int q = 0; q < 128; ++q)
        acc += b1[q] * W2[(128 + q) * 128 + c];
      bc[c] = acc;
    }
  }
}

// ===========================================================================
// CSR scans (round-12 proven)
// ===========================================================================
#define SCAN_NB 196  // ceil(200000/1024)

__global__ __launch_bounds__(256) void k_scan_a(const int* __restrict__ cnt,
                                                int* bsum) {
  __shared__ int sh[256];
  const int b = blockIdx.x, t = threadIdx.x;
  const int base = b * 1024 + t * 4;
  int s = 0;
  #pragma unroll
  for (int k = 0; k < 4; ++k) {
    const int idx = base + k;
    s += (idx < N_NODES) ? cnt[idx] : 0;
  }
  sh[t] = s; __syncthreads();
  for (int o = 128; o > 0; o >>= 1) {
    if (t < o) sh[t] += sh[t + o];
    __syncthreads();
  }
  if (t == 0) bsum[b] = sh[0];
}

__global__ __launch_bounds__(256) void k_scan_c2(const int* __restrict__ cnt,
                                                 const int* __restrict__ bsum,
                                                 int* offv) {
  __shared__ int sh[256];
  __shared__ int base_sh;
  const int b = blockIdx.x, t = threadIdx.x;

  sh[t] = (t < SCAN_NB && t < b) ? bsum[t] : 0;
  __syncthreads();
  for (int o = 128; o > 0; o >>= 1) {
    if (t < o) sh[t] += sh[t + o];
    __syncthreads();
  }
  if (t == 0) base_sh = sh[0];
  __syncthreads();

  const int base = b * 1024 + t * 4;
  int v[4], p[4], s = 0;
  #pragma unroll
  for (int k = 0; k < 4; ++k) {
    const int idx = base + k;
    v[k] = (idx < N_NODES) ? cnt[idx] : 0;
    p[k] = s; s += v[k];
  }
  sh[t] = s; __syncthreads();
  const int tot = s;
  for (int o = 1; o < 256; o <<= 1) {
    const int tv = (t >= o) ? sh[t - o] : 0;
    __syncthreads();
    sh[t] += tv;
    __syncthreads();
  }
  const int gb = base_sh + (sh[t] - tot);
  #pragma unroll
  for (int k = 0; k < 4; ++k) {
    const int idx = base + k;
    if (idx < N_NODES) offv[idx] = gb + p[k];
  }
}

// ===========================================================================
// k_placeprep2: modulo-interleaved  place (2:7)  ||  prepB nodes>=100k (5:7)
// ===========================================================================
__global__ __launch_bounds__(256) void k_placeprep2(
    const int* __restrict__ ei, const int* __restrict__ offv,
    const int* __restrict__ slot, const float* __restrict__ ea,
    int* __restrict__ psrc, short* __restrict__ ea_s,
    const float* __restrict__ x, short* __restrict__ xb)
{
  const int b = blockIdx.x;
  const int tid = threadIdx.x;
  const int g = b / 7, r = b % 7;
  if (r < 2) {                                    // place block (0..2499)
    const int e = (g * 2 + r) * 256 + tid;
    const int j = offv[ei[N_EDGES + e]] + slot[e];
    psrc[j] = ei[e];
    #pragma unroll
    for (int h = 0; h < 4; ++h) {
      const float4 w0 = *(const float4*)&ea[(size_t)e * D_EDGE + h * 8];
      const float4 w1 = *(const float4*)&ea[(size_t)e * D_EDGE + h * 8 + 4];
      bf16x8 o = { f2b(w0.x), f2b(w0.y), f2b(w0.z), f2b(w0.w),
                   f2b(w1.x), f2b(w1.y), f2b(w1.z), f2b(w1.w) };
      *(bf16x8*)&ea_s[(size_t)j * D_EDGE + h * 8] = o;
    }
  } else {                                        // prepB block (6250..12499)
    prep_body(x, xb, 6250 + g * 5 + (r - 2), tid);
  }
}

// ===========================================================================
// S aggregation (round-12 proven, dense arrays)
// ===========================================================================
__global__ __launch_bounds__(256) void k_sagg4(
    const int* __restrict__ offv, const int* __restrict__ cnt,
    const int* __restrict__ psrc, const short* __restrict__ xb,
    const short* __restrict__ ea_s,
    short* __restrict__ Sx, short* __restrict__ Se)
{
  const int gtid = blockIdx.x * 256 + threadIdx.x;
  if (gtid < N_NODES * 16) {
    const int node = gtid >> 4;
    const int oct8 = (gtid & 15) << 3;
    const int s0 = offv[node];
    const int s1 = s0 + cnt[node];
    float a[8] = {};
    int j = s0;
    while (j < s1) {
      const int rem = s1 - j;
      bf16x8 v0, v1, v2, v3;
      v0 = *(const bf16x8*)&xb[(size_t)psrc[j] * D_NODE + oct8];
      if (rem > 1) v1 = *(const bf16x8*)&xb[(size_t)psrc[j + 1] * D_NODE + oct8];
      if (rem > 2) v2 = *(const bf16x8*)&xb[(size_t)psrc[j + 2] * D_NODE + oct8];
      if (rem > 3) v3 = *(const bf16x8*)&xb[(size_t)psrc[j + 3] * D_NODE + oct8];
      #pragma unroll
      for (int k = 0; k < 8; ++k) a[k] += b2f(v0[k]);
      if (rem > 1) {
        #pragma unroll
        for (int k = 0; k < 8; ++k) a[k] += b2f(v1[k]);
      }
      if (rem > 2) {
        #pragma unroll
        for (int k = 0; k < 8; ++k) a[k] += b2f(v2[k]);
      }
      if (rem > 3) {
        #pragma unroll
        for (int k = 0; k < 8; ++k) a[k] += b2f(v3[k]);
      }
      j += 4;
    }
    bf16x8 o;
    #pragma unroll
    for (int k = 0; k < 8; ++k) o[k] = f2b(a[k]);
    *(bf16x8*)&Sx[(size_t)node * D_NODE + oct8] = o;
  } else {
    const int t2 = gtid - N_NODES * 16;       // 0 .. N_NODES*4
    const int node = t2 >> 2;
    const int q8   = (t2 & 3) << 3;           // 8 bf16 = 16B
    const int s0 = offv[node];
    const int s1 = s0 + cnt[node];
    float a[8] = {};
    for (int j = s0; j < s1; ++j) {
      const bf16x8 v = *(const bf16x8*)&ea_s[(size_t)j * D_EDGE + q8];
      #pragma unroll
      for (int k = 0; k < 8; ++k) a[k] += b2f(v[k]);
    }
    bf16x8 o;
    #pragma unroll
    for (int k = 0; k < 8; ++k) o[k] = f2b(a[k]);
    *(bf16x8*)&Se[(size_t)node * D_EDGE + q8] = o;
  }
}

// ===========================================================================
// Output GEMM (round-12 proven): out = [xb|Sx|Se] @ Wc + cnt*bc + b2.
// ===========================================================================
#define LDP 104   // 96+8 bf16: 208B rows -> 2-way bank alias only (free)

__global__ __launch_bounds__(256, 4) void k_out2(
    const short* __restrict__ xb, const short* __restrict__ Sx,
    const short* __restrict__ Se, const short* __restrict__ WcT,
    const float* __restrict__ bc, const float* __restrict__ b2,
    const int* __restrict__ cnt, float* __restrict__ out)
{
  __shared__ short smem[64 * LDP + 128 * LDP];   // 39936 B
  short* lA = smem;
  short* lB = smem + 64 * LDP;
  const int tid = threadIdx.x;
  const int n0  = blockIdx.x * 64;

  const int lane = tid & 63;
  const int wid  = tid >> 6;
  const int wm = wid >> 1, wn = wid & 1;          // 2x2 waves, 32x64 out each
  const int lrow = lane & 15;
  const int lk   = (lane >> 4) << 3;

  f32x4 acc[2][4] = {};

  #pragma unroll
  for (int p = 0; p < 3; ++p) {
    for (int i = tid; i < 1536; i += 256) {       // lB: 128 rows x 12 octs
      const int n = i / 12, ck = (i % 12) << 3;
      *(bf16x8*)&lB[n * LDP + ck] = *(const bf16x8*)&WcT[n * KTOT + p * 96 + ck];
    }
    for (int i = tid; i < 768; i += 256) {        // lA: 64 rows x 12 octs
      const int m = i / 12, ck = (i % 12) << 3;
      const int k = p * 96 + ck;
      const int node = n0 + m;
      const short* src;
      if (k < 128)      src = &xb[(size_t)node * D_NODE + k];
      else if (k < 256) src = &Sx[(size_t)node * D_NODE + (k - 128)];
      else              src = &Se[(size_t)node * D_EDGE + (k - 256)];
      *(bf16x8*)&lA[m * LDP + ck] = *(const bf16x8*)src;
    }
    __syncthreads();
    #pragma unroll
    for (int kt = 0; kt < 3; ++kt) {
      const int ks = kt * 32 + lk;
      bf16x8 af[2], bfr[4];
      #pragma unroll
      for (int i = 0; i < 2; ++i)
        af[i]  = *(const bf16x8*)&lA[(wm * 32 + i * 16 + lrow) * LDP + ks];
      #pragma unroll
      for (int j = 0; j < 4; ++j)
        bfr[j] = *(const bf16x8*)&lB[(wn * 64 + j * 16 + lrow) * LDP + ks];
      #pragma unroll
      for (int i = 0; i < 2; ++i)
        #pragma unroll
        for (int j = 0; j < 4; ++j)
          acc[i][j] = __builtin_amdgcn_mfma_f32_16x16x32_bf16(af[i], bfr[j], acc[i][j], 0, 0, 0);
    }
    __syncthreads();
  }

  // ---- epilogue: acc + cnt*bc + b2 -> LDS f32 [64][128] -> coalesced stores
  float* lf = (float*)smem;                       // 32768 B <= 39936 B
  const int rb = wm * 32 + ((lane >> 4) << 2);
  const int cb = wn * 64 + lrow;
  float bcv[4], b2v[4];
  #pragma unroll
  for (int j = 0; j < 4; ++j) {
    bcv[j] = bc[cb + j * 16];
    b2v[j] = b2[cb + j * 16];
  }
  #pragma unroll
  for (int i = 0; i < 2; ++i) {
    #pragma unroll
    for (int r = 0; r < 4; ++r) {
      const int row = rb + i * 16 + r;
      const float cf = (float)cnt[n0 + row];
      #pragma unroll
      for (int j = 0; j < 4; ++j)
        lf[row * 128 + cb + j * 16] = acc[i][j][r] + cf * bcv[j] + b2v[j];
    }
  }
  __syncthreads();
  #pragma unroll
  for (int u = 0; u < 8; ++u) {
    const int idx = tid + u * 256;                // 2048 float4s
    const int row = idx >> 5, f4 = (idx & 31) << 2;
    *(float4*)&out[(size_t)(n0 + row) * HIDDEN + f4] = *(const float4*)&lf[row * 128 + f4];
  }
}

extern "C" void kernel_launch(void* const* d_in, const int* in_sizes, int n_in,
                              void* d_out, int out_size, void* d_ws, size_t ws_size,
                              hipStream_t stream) {
  const float* x  = (const float*)d_in[0];
  const int*   ei = (const int*)d_in[1];
  const float* ea = (const float*)d_in[2];
  const float* W1 = (const float*)d_in[5];
  const float* b1 = (const float*)d_in[6];
  const float* W2 = (const float*)d_in[7];
  const float* b2 = (const float*)d_in[8];
  float* out = (float*)d_out;

  const size_t XB_B   = (size_t)N_NODES * D_NODE * 2; //  51,200,000
  const size_t SX_B   = (size_t)N_NODES * D_NODE * 2; //  51,200,000
  const size_t SE_B   = (size_t)N_NODES * D_EDGE * 2; //  12,800,000
  const size_t WCT_B  = 128 * KTOT * 2;               //      73,728
  const size_t BC_B   = 512;
  const size_t CNT_B  = (size_t)N_NODES * 4;          //     800,000
  const size_t SLOT_B = (size_t)N_EDGES * 4;          //   2,560,000
  const size_t PSRC_B = (size_t)N_EDGES * 4;          //   2,560,000
  const size_t EAS_B  = (size_t)N_EDGES * D_EDGE * 2; //  40,960,000

  const size_t o_xb   = 0;
  const size_t o_sx   = o_xb + XB_B;
  const size_t o_se   = o_sx + SX_B;
  const size_t o_wct  = o_se + SE_B;
  const size_t o_bc   = o_wct + WCT_B;
  const size_t o_cnt  = o_bc + BC_B;
  const size_t o_off  = o_cnt + CNT_B;
  const size_t o_slot = o_off + CNT_B;
  const size_t o_psrc = o_slot + SLOT_B;
  const size_t o_eas  = o_psrc + PSRC_B;
  const size_t o_bsum = o_eas + EAS_B;
  // total ~163.7 MB (round-12 plan fit)

  short* xb   = (short*)((char*)d_ws + o_xb);
  short* Sx   = (short*)((char*)d_ws + o_sx);
  short* Se   = (short*)((char*)d_ws + o_se);
  short* WcT  = (short*)((char*)d_ws + o_wct);
  float* bc   = (float*)((char*)d_ws + o_bc);
  int*   cnt  = (int*)((char*)d_ws + o_cnt);
  int*   offv = (int*)((char*)d_ws + o_off);
  int*   slot = (int*)((char*)d_ws + o_slot);
  int*   psrc = (int*)((char*)d_ws + o_psrc);
  short* ea_s = (short*)((char*)d_ws + o_eas);
  int*   bsum = (int*)((char*)d_ws + o_bsum);

  hipMemsetAsync(cnt, 0, CNT_B, stream);
  k_histprep<<<MIX_NB + WC_NB, 256, 0, stream>>>(ei, cnt, slot, x, xb,
                                                 W1, b1, W2, WcT, bc);

  k_scan_a <<<SCAN_NB, 256, 0, stream>>>(cnt, bsum);
  k_scan_c2<<<SCAN_NB, 256, 0, stream>>>(cnt, bsum, offv);

  k_placeprep2<<<MIX_NB, 256, 0, stream>>>(ei, offv, slot, ea,
                                           psrc, ea_s, x, xb);

  k_sagg4<<<(N_NODES * 20) / 256, 256, 0, stream>>>(offv, cnt, psrc, xb, ea_s, Sx, Se);
  k_out2 <<<N_NODES / 64, 256, 0, stream>>>(xb, Sx, Se, WcT, bc, b2, cnt, out);
}